// Round 19
// baseline (569.055 us; speedup 1.0000x reference)
//
#include <hip/hip_runtime.h>
#include <hip/hip_bf16.h>

// q = rownorm( 1 / (1 + ||x - c||^2) ), ALPHA=1
// x: (262144, 256) f32 ; clusters: (256, 256) f32 ; out: (262144, 256) f32
//
// R20: full-width waves, ZERO steady-state synchronization. Each wave owns
// 16 rows x ALL 256 cols -> row sums are wave-local; the pair handshake
// (and its skew coupling + 2x x-load duplication) is gone entirely.
// R9's full-width spilled at ~144 regs; this fits the measured 128-arch
// envelope via: single reused xv[8] (32), half-afrag pipeline (afA/afB[4],
// disjoint lifetimes), csq in LDS (-16). Peak ~= acc 64 + af 16 + xv 32
// + temps ~= 120 (= R17's measured envelope). Cost: WAR serialization on
// xv (loads wait for convert) — covered by the 64-MFMA clusters.

#define NROWS 262144
#define DDIM  256
#define KCL   256
#define TPB   8                       // 128-row tiles per block
#define GRID  (NROWS / 128 / TPB)     // 256 blocks = 1 per CU

using f32x4  = __attribute__((ext_vector_type(4))) float;
using s16x8  = __attribute__((ext_vector_type(8))) short;

__device__ inline unsigned short f2bf(float f) {
    // round-to-nearest-even f32 -> bf16 (prep kernel)
    unsigned int u = __float_as_uint(f);
    u += 0x7fffu + ((u >> 16) & 1u);
    return (unsigned short)(u >> 16);
}

__device__ inline short bfc(float f) {
    // cast-based: pairs into v_cvt_pk_bf16_f32 (same RTNE result)
    return (short)__bfloat16_as_ushort(__float2bfloat16(f));
}

// One wave per cluster row: convert to bf16, compute ||c||^2.
__global__ void prep_kernel(const float* __restrict__ clusters,
                            unsigned short* __restrict__ cb,
                            float* __restrict__ csq) {
    int k    = blockIdx.x;
    int lane = threadIdx.x;  // 64 threads
    const float* row = clusters + (size_t)k * DDIM;
    float4 a = *reinterpret_cast<const float4*>(row + lane * 4);
    ushort4 b;
    b.x = f2bf(a.x); b.y = f2bf(a.y); b.z = f2bf(a.z); b.w = f2bf(a.w);
    *reinterpret_cast<ushort4*>(cb + (size_t)k * DDIM + lane * 4) = b;
    float ss = a.x*a.x + a.y*a.y + a.z*a.z + a.w*a.w;
    #pragma unroll
    for (int m = 1; m < 64; m <<= 1) ss += __shfl_xor(ss, m);
    if (lane == 0) csq[k] = ss;
}

// 8 waves/block; wave owns 16 rows x 256 cols per tile; no cross-wave deps.
// A-frag: lane holds x[row + (l&15)][s*32 + (l>>4)*8 + j], j=0..7
// B-frag: lane holds c[f*16 + (l&15)][s*32 + (l>>4)*8 + j], f=0..15
// C/D   : col = l&15, row = (l>>4)*4 + reg   [verified layout, m89]
__global__ __launch_bounds__(512, 2) void fused_kernel(
    const float* __restrict__ x,
    const unsigned short* __restrict__ cb,
    const float* __restrict__ csq,
    float* __restrict__ out) {

    __shared__ char  lds_b[KCL * DDIM * 2];   // 128 KB: full B, swizzled
    __shared__ float ls_csq[KCL];             // 1 KB: ||c||^2

    const int tid  = threadIdx.x;
    const int lane = tid & 63;
    const int wave = tid >> 6;               // 0..7
    const int c15  = lane & 15;
    const int kch  = lane >> 4;              // 0..3

    const int rowblk = blockIdx.x * (TPB * 128);

    // ---- stage full B into LDS (linear dest, swizzled global source) ----
    #pragma unroll
    for (int it = 0; it < 16; ++it) {
        int slot = it * 8192 + tid * 16;
        int src  = slot ^ (((slot >> 9) & 7) << 4);
        __builtin_amdgcn_global_load_lds(
            (const __attribute__((address_space(1))) unsigned int*)((const char*)cb + src),
            (__attribute__((address_space(3))) unsigned int*)(lds_b + slot),
            16, 0, 0);
    }
    if (tid < KCL) ls_csq[tid] = csq[tid];

    // per-lane x base for tile t (this wave's 16 rows, lane's k-chunk)
    auto xrow = [&](int t) -> const float* {
        return x + (size_t)(rowblk + t * 128 + wave * 16 + c15) * DDIM + kch * 8;
    };

    f32x4 xv[8];   // SINGLE reused load buffer (32 regs)

    // ---- prologue: tile 0's first k-half flies under B staging ----
    #pragma unroll
    for (int i = 0; i < 8; ++i)
        xv[i] = *reinterpret_cast<const f32x4*>(xrow(0) + (i >> 1) * 32 + (i & 1) * 4);

    __syncthreads();   // drains vmcnt; B + csq ready — the ONLY barrier

    #pragma unroll 1
    for (int t = 0; t < TPB; ++t) {
        const int row0t = rowblk + t * 128 + wave * 16;
        const float* xr = xrow(t);

        float p0 = 0.f, p1 = 0.f;

        // ---- convert half 1 (k 0..127) -> afA; xv dies ----
        s16x8 afA[4];
        #pragma unroll
        for (int s4 = 0; s4 < 4; ++s4) {
            f32x4 xa = xv[2 * s4], xb = xv[2 * s4 + 1];
            float t0 = xa[0]*xa[0] + xa[1]*xa[1];
            float t1 = xa[2]*xa[2] + xa[3]*xa[3];
            float t2 = xb[0]*xb[0] + xb[1]*xb[1];
            float t3 = xb[2]*xb[2] + xb[3]*xb[3];
            if (s4 & 1) p1 += (t0 + t1) + (t2 + t3);
            else        p0 += (t0 + t1) + (t2 + t3);
            afA[s4][0] = bfc(xa[0]); afA[s4][1] = bfc(xa[1]);
            afA[s4][2] = bfc(xa[2]); afA[s4][3] = bfc(xa[3]);
            afA[s4][4] = bfc(xb[0]); afA[s4][5] = bfc(xb[1]);
            afA[s4][6] = bfc(xb[2]); afA[s4][7] = bfc(xb[3]);
        }

        // ---- reload xv with half 2; MFMA s0-3 covers its latency ----
        #pragma unroll
        for (int i = 0; i < 8; ++i) {
            int ii = 8 + i;
            xv[i] = *reinterpret_cast<const f32x4*>(xr + (ii >> 1) * 32 + (ii & 1) * 4);
        }

        f32x4 acc[16];
        #pragma unroll
        for (int f = 0; f < 16; ++f) acc[f] = (f32x4){0.f, 0.f, 0.f, 0.f};

        __builtin_amdgcn_s_setprio(1);
        #pragma unroll
        for (int s = 0; s < 4; ++s) {
            #pragma unroll
            for (int f = 0; f < 16; ++f) {
                int ba = ((f * 16 + c15) * 512) + s * 64 + kch * 16;
                ba ^= ((c15 & 7) << 4);
                s16x8 bfrag = *reinterpret_cast<const s16x8*>(lds_b + ba);
                acc[f] = __builtin_amdgcn_mfma_f32_16x16x32_bf16(afA[s], bfrag,
                                                                 acc[f], 0, 0, 0);
            }
        }
        __builtin_amdgcn_s_setprio(0);

        // ---- convert half 2 -> afB; xv dies ----
        s16x8 afB[4];
        #pragma unroll
        for (int s4 = 0; s4 < 4; ++s4) {
            f32x4 xa = xv[2 * s4], xb = xv[2 * s4 + 1];
            float t0 = xa[0]*xa[0] + xa[1]*xa[1];
            float t1 = xa[2]*xa[2] + xa[3]*xa[3];
            float t2 = xb[0]*xb[0] + xb[1]*xb[1];
            float t3 = xb[2]*xb[2] + xb[3]*xb[3];
            if (s4 & 1) p1 += (t0 + t1) + (t2 + t3);
            else        p0 += (t0 + t1) + (t2 + t3);
            afB[s4][0] = bfc(xa[0]); afB[s4][1] = bfc(xa[1]);
            afB[s4][2] = bfc(xa[2]); afB[s4][3] = bfc(xa[3]);
            afB[s4][4] = bfc(xb[0]); afB[s4][5] = bfc(xb[1]);
            afB[s4][6] = bfc(xb[2]); afB[s4][7] = bfc(xb[3]);
        }

        // ---- reload xv with NEXT tile's half 1 (flies through MFMA+epilogue) ----
        if (t + 1 < TPB) {
            const float* xn = xrow(t + 1);
            #pragma unroll
            for (int i = 0; i < 8; ++i)
                xv[i] = *reinterpret_cast<const f32x4*>(xn + (i >> 1) * 32 + (i & 1) * 4);
        }

        __builtin_amdgcn_s_setprio(1);
        #pragma unroll
        for (int s = 0; s < 4; ++s) {
            #pragma unroll
            for (int f = 0; f < 16; ++f) {
                int ba = ((f * 16 + c15) * 512) + (s + 4) * 64 + kch * 16;
                ba ^= ((c15 & 7) << 4);
                s16x8 bfrag = *reinterpret_cast<const s16x8*>(lds_b + ba);
                acc[f] = __builtin_amdgcn_mfma_f32_16x16x32_bf16(afB[s], bfrag,
                                                                 acc[f], 0, 0, 0);
            }
        }
        __builtin_amdgcn_s_setprio(0);

        // ---- epilogue: student-t + WAVE-LOCAL row sums (no handshake) ----
        float xsq = p0 + p1;
        xsq += __shfl_xor(xsq, 16);
        xsq += __shfl_xor(xsq, 32);
        // lane l now holds xsq of row row0t + (l&15)

        float xr4[4], srow[4];
        #pragma unroll
        for (int r = 0; r < 4; ++r) {
            xr4[r]  = __shfl(xsq, kch * 4 + r);
            srow[r] = 0.f;
        }
        #pragma unroll
        for (int f = 0; f < 16; ++f) {
            float cf = ls_csq[f * 16 + c15];
            #pragma unroll
            for (int r = 0; r < 4; ++r) {
                float d2 = xr4[r] - 2.0f * acc[f][r] + cf;
                float qv = __builtin_amdgcn_rcpf(1.0f + d2);  // ALPHA=1 -> exp==1
                acc[f][r] = qv;
                srow[r] += qv;
            }
        }
        #pragma unroll
        for (int r = 0; r < 4; ++r) {
            float s = srow[r];
            s += __shfl_xor(s, 1);
            s += __shfl_xor(s, 2);
            s += __shfl_xor(s, 4);
            s += __shfl_xor(s, 8);
            float inv = __builtin_amdgcn_rcpf(s);
            const size_t orow = (size_t)(row0t + kch * 4 + r) * KCL;
            #pragma unroll
            for (int f = 0; f < 16; ++f) {
                __builtin_nontemporal_store(acc[f][r] * inv, &out[orow + f * 16 + c15]);
            }
        }
    }
}

extern "C" void kernel_launch(void* const* d_in, const int* in_sizes, int n_in,
                              void* d_out, int out_size, void* d_ws, size_t ws_size,
                              hipStream_t stream) {
    const float* x        = (const float*)d_in[0];
    const float* clusters = (const float*)d_in[1];
    float* out = (float*)d_out;

    // ws layout: [0, 128KB) clusters as bf16 ; [128KB, +1KB) c_sq f32
    unsigned short* cb  = (unsigned short*)d_ws;
    float*          csq = (float*)((char*)d_ws + (size_t)KCL * DDIM * sizeof(unsigned short));

    prep_kernel<<<KCL, 64, 0, stream>>>(clusters, cb, csq);
    fused_kernel<<<GRID, 512, 0, stream>>>(x, cb, csq, out);
}

// Round 20
// 138.599 us; speedup vs baseline: 4.1057x; 4.1057x over previous
//
#include <hip/hip_runtime.h>
#include <hip/hip_bf16.h>

// q = rownorm( 1 / (1 + ||x - c||^2) ), ALPHA=1
// x: (262144, 256) f32 ; clusters: (256, 256) f32 ; out: (262144, 256) f32
//
// R21: R17 (126.6us champion — col-split wave pairs, pairwise flag sync,
// setprio, s_sleep spin, 120 regs no-spill) + SWAPPED MFMA OPERANDS.
// mfma(cl_frag, x_frag) computes D[cluster][xrow] (legal with zero layout
// changes: A/B fragment lane layouts are identical for 16x16x32). New C/D
// mapping: lane holds xrow = l&15, cluster = f*16 + kch*4 + reg. Epilogue:
//  (1) stores become float4 NT (8x16B vs 32x4B; clean 64B/lane-quad),
//  (2) xsq broadcast eliminated (lane already holds its row's xsq),
//  (3) row-sum = 32 lane-local adds + 2 shfl_xor (was 16 shfl + 4 bcast).
// csq moved to LDS (frees cs[8]; one broadcast ds_read_b128 per f).

#define NROWS 262144
#define DDIM  256
#define KCL   256
#define TPB   16                      // 64-row tiles per block
#define GRID  (NROWS / 64 / TPB)      // 256 blocks = 1 per CU

using f32x4  = __attribute__((ext_vector_type(4))) float;
using s16x8  = __attribute__((ext_vector_type(8))) short;

__device__ inline unsigned short f2bf(float f) {
    // round-to-nearest-even f32 -> bf16 (prep kernel)
    unsigned int u = __float_as_uint(f);
    u += 0x7fffu + ((u >> 16) & 1u);
    return (unsigned short)(u >> 16);
}

__device__ inline short bfc(float f) {
    // cast-based: pairs into v_cvt_pk_bf16_f32 (same RTNE result)
    return (short)__bfloat16_as_ushort(__float2bfloat16(f));
}

// One wave per cluster row: convert to bf16, compute ||c||^2.
__global__ void prep_kernel(const float* __restrict__ clusters,
                            unsigned short* __restrict__ cb,
                            float* __restrict__ csq) {
    int k    = blockIdx.x;
    int lane = threadIdx.x;  // 64 threads
    const float* row = clusters + (size_t)k * DDIM;
    float4 a = *reinterpret_cast<const float4*>(row + lane * 4);
    ushort4 b;
    b.x = f2bf(a.x); b.y = f2bf(a.y); b.z = f2bf(a.z); b.w = f2bf(a.w);
    *reinterpret_cast<ushort4*>(cb + (size_t)k * DDIM + lane * 4) = b;
    float ss = a.x*a.x + a.y*a.y + a.z*a.z + a.w*a.w;
    #pragma unroll
    for (int m = 1; m < 64; m <<= 1) ss += __shfl_xor(ss, m);
    if (lane == 0) csq[k] = ss;
}

// 8 waves/block: wave w -> rg = w>>1 (pair), ch = w&1 (col half).
// Wave computes rows [trow+rg*16, +16) x clusters [ch*128, +128).
// x-frag (passed as MFMA operand B): lane holds x[row0+(l&15)][s*32+(l>>4)*8+j]
// cl-frag (passed as MFMA operand A): lane holds c[ch*128+f*16+(l&15)][...]
// D = cl . x^T : lane holds xrow = l&15, cluster = f*16 + kch*4 + reg.
__global__ __launch_bounds__(512, 2) void fused_kernel(
    const float* __restrict__ x,
    const unsigned short* __restrict__ cb,
    const float* __restrict__ csq,
    float* __restrict__ out) {

    __shared__ char  lds_b[KCL * DDIM * 2];   // 128 KB: full B, swizzled
    __shared__ float ls_csq[KCL];             // 1 KB: ||c||^2
    __shared__ float ls_sum[TPB][2][4][16];   // per-tile slots: no reuse hazard
    __shared__ int   ls_flag[2][4];           // [ch][rg] tiles-completed counter

    const int tid  = threadIdx.x;
    const int lane = tid & 63;
    const int wave = tid >> 6;               // 0..7
    const int rg   = wave >> 1;              // 0..3
    const int ch   = wave & 1;               // 0..1
    const int c15  = lane & 15;
    const int kch  = lane >> 4;              // 0..3

    const int tile0 = blockIdx.x * TPB;

    // ---- stage full B into LDS (linear dest, swizzled global source) ----
    #pragma unroll
    for (int it = 0; it < 16; ++it) {
        int slot = it * 8192 + tid * 16;
        int src  = slot ^ (((slot >> 9) & 7) << 4);
        __builtin_amdgcn_global_load_lds(
            (const __attribute__((address_space(1))) unsigned int*)((const char*)cb + src),
            (__attribute__((address_space(3))) unsigned int*)(lds_b + slot),
            16, 0, 0);
    }
    if (tid < KCL) ls_csq[tid] = csq[tid];
    if (tid < 8) ((int*)ls_flag)[tid] = 0;

    __syncthreads();   // drains vmcnt; B + csq + flags ready (only barrier)

    // per-lane x base for tile t
    auto xrow = [&](int t) -> const float* {
        return x + (size_t)((tile0 + t) * 64 + rg * 16 + c15) * DDIM + kch * 8;
    };

    f32x4 xv1[8], xv2[8];

    // ---- prologue: issue tile 0's first k-half ----
    {
        const float* xr = xrow(0);
        #pragma unroll
        for (int i = 0; i < 8; ++i)
            xv1[i] = *reinterpret_cast<const f32x4*>(xr + (i >> 1) * 32 + (i & 1) * 4);
    }

    #pragma unroll 1
    for (int t = 0; t < TPB; ++t) {
        const int trow = (tile0 + t) * 64;
        const float* xr = xrow(t);

        // ---- issue batch 2 (k 128..255) at strip TOP ----
        #pragma unroll
        for (int i = 0; i < 8; ++i) {
            int ii = 8 + i;
            xv2[i] = *reinterpret_cast<const f32x4*>(xr + (ii >> 1) * 32 + (ii & 1) * 4);
        }

        s16x8 afrag[8];
        float p[4] = {0.f, 0.f, 0.f, 0.f};

        // ---- convert batch 1 (k 0..127) -> afrag[0..3] ----
        #pragma unroll
        for (int s4 = 0; s4 < 4; ++s4) {
            f32x4 xa = xv1[2 * s4], xb = xv1[2 * s4 + 1];
            float t0 = xa[0]*xa[0] + xa[1]*xa[1];
            float t1 = xa[2]*xa[2] + xa[3]*xa[3];
            float t2 = xb[0]*xb[0] + xb[1]*xb[1];
            float t3 = xb[2]*xb[2] + xb[3]*xb[3];
            p[s4] += (t0 + t1) + (t2 + t3);
            afrag[s4][0] = bfc(xa[0]); afrag[s4][1] = bfc(xa[1]);
            afrag[s4][2] = bfc(xa[2]); afrag[s4][3] = bfc(xa[3]);
            afrag[s4][4] = bfc(xb[0]); afrag[s4][5] = bfc(xb[1]);
            afrag[s4][6] = bfc(xb[2]); afrag[s4][7] = bfc(xb[3]);
        }

        f32x4 acc[8];
        #pragma unroll
        for (int f = 0; f < 8; ++f) acc[f] = (f32x4){0.f, 0.f, 0.f, 0.f};

        __builtin_amdgcn_s_setprio(1);
        #pragma unroll
        for (int s = 0; s < 4; ++s) {
            #pragma unroll
            for (int f = 0; f < 8; ++f) {
                int ba = ((ch * 128 + f * 16 + c15) * 512) + s * 64 + kch * 16;
                ba ^= ((c15 & 7) << 4);
                s16x8 bfrag = *reinterpret_cast<const s16x8*>(lds_b + ba);
                // SWAPPED: D[cluster][xrow]
                acc[f] = __builtin_amdgcn_mfma_f32_16x16x32_bf16(bfrag, afrag[s],
                                                                 acc[f], 0, 0, 0);
            }
        }
        __builtin_amdgcn_s_setprio(0);

        // ---- convert batch 2 (k 128..255) -> afrag[4..7] ----
        #pragma unroll
        for (int s4 = 0; s4 < 4; ++s4) {
            f32x4 xa = xv2[2 * s4], xb = xv2[2 * s4 + 1];
            float t0 = xa[0]*xa[0] + xa[1]*xa[1];
            float t1 = xa[2]*xa[2] + xa[3]*xa[3];
            float t2 = xb[0]*xb[0] + xb[1]*xb[1];
            float t3 = xb[2]*xb[2] + xb[3]*xb[3];
            p[s4] += (t0 + t1) + (t2 + t3);
            int s = 4 + s4;
            afrag[s][0] = bfc(xa[0]); afrag[s][1] = bfc(xa[1]);
            afrag[s][2] = bfc(xa[2]); afrag[s][3] = bfc(xa[3]);
            afrag[s][4] = bfc(xb[0]); afrag[s][5] = bfc(xb[1]);
            afrag[s][6] = bfc(xb[2]); afrag[s][7] = bfc(xb[3]);
        }

        // ---- prefetch next tile's batch 1: flies through epilogue+sync ----
        if (t + 1 < TPB) {
            const float* xn = xrow(t + 1);
            #pragma unroll
            for (int i = 0; i < 8; ++i)
                xv1[i] = *reinterpret_cast<const f32x4*>(xn + (i >> 1) * 32 + (i & 1) * 4);
        }

        __builtin_amdgcn_s_setprio(1);
        #pragma unroll
        for (int s = 4; s < 8; ++s) {
            #pragma unroll
            for (int f = 0; f < 8; ++f) {
                int ba = ((ch * 128 + f * 16 + c15) * 512) + s * 64 + kch * 16;
                ba ^= ((c15 & 7) << 4);
                s16x8 bfrag = *reinterpret_cast<const s16x8*>(lds_b + ba);
                acc[f] = __builtin_amdgcn_mfma_f32_16x16x32_bf16(bfrag, afrag[s],
                                                                 acc[f], 0, 0, 0);
            }
        }
        __builtin_amdgcn_s_setprio(0);

        // ---- epilogue (swapped layout): lane owns row l&15, 32 clusters ----
        float xsq = (p[0] + p[1]) + (p[2] + p[3]);
        xsq += __shfl_xor(xsq, 16);
        xsq += __shfl_xor(xsq, 32);
        // lane l holds xsq of row trow + rg*16 + (l&15) — its OWN row

        float srow = 0.f;
        #pragma unroll
        for (int f = 0; f < 8; ++f) {
            f32x4 cq = *reinterpret_cast<const f32x4*>(&ls_csq[ch * 128 + f * 16 + kch * 4]);
            #pragma unroll
            for (int r = 0; r < 4; ++r) {
                float d2 = xsq - 2.0f * acc[f][r] + cq[r];
                float qv = __builtin_amdgcn_rcpf(1.0f + d2);  // ALPHA=1 -> exp==1
                acc[f][r] = qv;
                srow += qv;
            }
        }
        // combine the 4 kch partials: lane l -> sum over this wave's 128 cl
        srow += __shfl_xor(srow, 16);
        srow += __shfl_xor(srow, 32);

        // ---- pairwise handshake ----
        if (kch == 0) ls_sum[t][ch][rg][c15] = srow;
        asm volatile("s_waitcnt lgkmcnt(0)" ::: "memory");  // sums visible
        if (lane == 0)
            __atomic_store_n(&ls_flag[ch][rg], t + 1, __ATOMIC_RELAXED);

        volatile int* pf = (volatile int*)&ls_flag[ch ^ 1][rg];
        while (*pf <= t) { __builtin_amdgcn_s_sleep(1); }
        asm volatile("" ::: "memory");   // no hoisting of sum reads above spin

        float other = ls_sum[t][ch ^ 1][rg][c15];
        float inv = __builtin_amdgcn_rcpf(srow + other);

        // ---- float4 NT stores: lane writes 4 consecutive cluster cols ----
        const size_t obase = (size_t)(trow + rg * 16 + c15) * KCL + ch * 128 + kch * 4;
        #pragma unroll
        for (int f = 0; f < 8; ++f) {
            f32x4 v = { acc[f][0] * inv, acc[f][1] * inv,
                        acc[f][2] * inv, acc[f][3] * inv };
            __builtin_nontemporal_store(v, reinterpret_cast<f32x4*>(out + obase + f * 16));
        }
    }
}

extern "C" void kernel_launch(void* const* d_in, const int* in_sizes, int n_in,
                              void* d_out, int out_size, void* d_ws, size_t ws_size,
                              hipStream_t stream) {
    const float* x        = (const float*)d_in[0];
    const float* clusters = (const float*)d_in[1];
    float* out = (float*)d_out;

    // ws layout: [0, 128KB) clusters as bf16 ; [128KB, +1KB) c_sq f32
    unsigned short* cb  = (unsigned short*)d_ws;
    float*          csq = (float*)((char*)d_ws + (size_t)KCL * DDIM * sizeof(unsigned short));

    prep_kernel<<<KCL, 64, 0, stream>>>(clusters, cb, csq);
    fused_kernel<<<GRID, 512, 0, stream>>>(x, cb, csq, out);
}

// Round 21
// 127.197 us; speedup vs baseline: 4.4738x; 1.0896x over previous
//
#include <hip/hip_runtime.h>

// q = rownorm( 1 / (1 + ||x - c||^2) ), ALPHA=1
// x: (262144, 256) f32 ; clusters: (256, 256) f32 ; out: (262144, 256) f32
//
// R22 = exact revert to R17, the measured champion (126.6 us, VGPR=120,
// no spill). Structure: full B (128KB, swizzled) in LDS once per block;
// 8 waves = 4 col-split pairs; per-tile pairwise LDS-flag handshake (no
// block barrier, no vmcnt drain); xv2 issued at strip top, xv1(t+1) after
// MFMAs; rcpf student-t epilogue; NT stores; setprio around MFMA clusters;
// s_sleep spin. All structural escapes from this envelope were falsified
// with counter evidence (R9/R11-R16, R19-R21): the 128-arch register cap
// at 2 waves/SIMD is the binding constraint.

#define NROWS 262144
#define DDIM  256
#define KCL   256
#define TPB   16                      // 64-row tiles per block
#define GRID  (NROWS / 64 / TPB)      // 256 blocks = 1 per CU

using f32x4  = __attribute__((ext_vector_type(4))) float;
using s16x8  = __attribute__((ext_vector_type(8))) short;

__device__ inline unsigned short f2bf(float f) {
    // round-to-nearest-even f32 -> bf16
    unsigned int u = __float_as_uint(f);
    u += 0x7fffu + ((u >> 16) & 1u);
    return (unsigned short)(u >> 16);
}

// One wave per cluster row: convert to bf16, compute ||c||^2.
__global__ void prep_kernel(const float* __restrict__ clusters,
                            unsigned short* __restrict__ cb,
                            float* __restrict__ csq) {
    int k    = blockIdx.x;
    int lane = threadIdx.x;  // 64 threads
    const float* row = clusters + (size_t)k * DDIM;
    float4 a = *reinterpret_cast<const float4*>(row + lane * 4);
    ushort4 b;
    b.x = f2bf(a.x); b.y = f2bf(a.y); b.z = f2bf(a.z); b.w = f2bf(a.w);
    *reinterpret_cast<ushort4*>(cb + (size_t)k * DDIM + lane * 4) = b;
    float ss = a.x*a.x + a.y*a.y + a.z*a.z + a.w*a.w;
    #pragma unroll
    for (int m = 1; m < 64; m <<= 1) ss += __shfl_xor(ss, m);
    if (lane == 0) csq[k] = ss;
}

// 8 waves/block: wave w -> rg = w>>1 (pair), ch = w&1 (col half).
// Wave computes rows [trow+rg*16, +16) x cols [ch*128, +128).
// A-frag: lane holds x[row + (l&15)][s*32 + (l>>4)*8 + j], j=0..7
// B-frag: lane holds c[ch*128 + f*16 + (l&15)][s*32 + (l>>4)*8 + j], f=0..7
// C/D   : col = l&15, row = (l>>4)*4 + reg   [verified layout, m89]
__global__ __launch_bounds__(512, 2) void fused_kernel(
    const float* __restrict__ x,
    const unsigned short* __restrict__ cb,
    const float* __restrict__ csq,
    float* __restrict__ out) {

    __shared__ char  lds_b[KCL * DDIM * 2];   // 128 KB: full B, swizzled
    __shared__ float ls_sum[TPB][2][4][16];   // per-tile slots: no reuse hazard
    __shared__ int   ls_flag[2][4];           // [ch][rg] tiles-completed counter

    const int tid  = threadIdx.x;
    const int lane = tid & 63;
    const int wave = tid >> 6;               // 0..7
    const int rg   = wave >> 1;              // 0..3
    const int ch   = wave & 1;               // 0..1
    const int c15  = lane & 15;
    const int kch  = lane >> 4;              // 0..3

    const int tile0 = blockIdx.x * TPB;

    // ---- stage full B into LDS (linear dest, swizzled global source) ----
    #pragma unroll
    for (int it = 0; it < 16; ++it) {
        int slot = it * 8192 + tid * 16;
        int src  = slot ^ (((slot >> 9) & 7) << 4);
        __builtin_amdgcn_global_load_lds(
            (const __attribute__((address_space(1))) unsigned int*)((const char*)cb + src),
            (__attribute__((address_space(3))) unsigned int*)(lds_b + slot),
            16, 0, 0);
    }

    if (tid < 8) ((int*)ls_flag)[tid] = 0;

    // csq fragment for this wave's col half (8 regs)
    float cs[8];
    #pragma unroll
    for (int f = 0; f < 8; ++f) cs[f] = csq[ch * 128 + f * 16 + c15];

    __syncthreads();   // drains vmcnt; B + flags ready (only block barrier)

    // per-lane x base for tile t
    auto xrow = [&](int t) -> const float* {
        return x + (size_t)((tile0 + t) * 64 + rg * 16 + c15) * DDIM + kch * 8;
    };

    f32x4 xv1[8], xv2[8];

    // ---- prologue: issue tile 0's first k-half ----
    {
        const float* xr = xrow(0);
        #pragma unroll
        for (int i = 0; i < 8; ++i)
            xv1[i] = *reinterpret_cast<const f32x4*>(xr + (i >> 1) * 32 + (i & 1) * 4);
    }

    #pragma unroll 1
    for (int t = 0; t < TPB; ++t) {
        const int trow = (tile0 + t) * 64;
        const float* xr = xrow(t);

        // ---- issue batch 2 (k 128..255) at strip TOP: convert-1 + MFMA
        //      s0-3 cover its full HBM latency ----
        #pragma unroll
        for (int i = 0; i < 8; ++i) {
            int ii = 8 + i;
            xv2[i] = *reinterpret_cast<const f32x4*>(xr + (ii >> 1) * 32 + (ii & 1) * 4);
        }

        s16x8 afrag[8];
        float p[4] = {0.f, 0.f, 0.f, 0.f};

        // ---- convert batch 1 (k 0..127) -> afrag[0..3] ----
        #pragma unroll
        for (int s4 = 0; s4 < 4; ++s4) {
            f32x4 xa = xv1[2 * s4], xb = xv1[2 * s4 + 1];
            float t0 = xa[0]*xa[0] + xa[1]*xa[1];
            float t1 = xa[2]*xa[2] + xa[3]*xa[3];
            float t2 = xb[0]*xb[0] + xb[1]*xb[1];
            float t3 = xb[2]*xb[2] + xb[3]*xb[3];
            p[s4] += (t0 + t1) + (t2 + t3);
            afrag[s4][0] = (short)f2bf(xa[0]); afrag[s4][1] = (short)f2bf(xa[1]);
            afrag[s4][2] = (short)f2bf(xa[2]); afrag[s4][3] = (short)f2bf(xa[3]);
            afrag[s4][4] = (short)f2bf(xb[0]); afrag[s4][5] = (short)f2bf(xb[1]);
            afrag[s4][6] = (short)f2bf(xb[2]); afrag[s4][7] = (short)f2bf(xb[3]);
        }

        f32x4 acc[8];
        #pragma unroll
        for (int f = 0; f < 8; ++f) acc[f] = (f32x4){0.f, 0.f, 0.f, 0.f};

        __builtin_amdgcn_s_setprio(1);
        #pragma unroll
        for (int s = 0; s < 4; ++s) {
            #pragma unroll
            for (int f = 0; f < 8; ++f) {
                int ba = ((ch * 128 + f * 16 + c15) * 512) + s * 64 + kch * 16;
                ba ^= ((c15 & 7) << 4);
                s16x8 bfrag = *reinterpret_cast<const s16x8*>(lds_b + ba);
                acc[f] = __builtin_amdgcn_mfma_f32_16x16x32_bf16(afrag[s], bfrag,
                                                                 acc[f], 0, 0, 0);
            }
        }
        __builtin_amdgcn_s_setprio(0);

        // ---- convert batch 2 (k 128..255) -> afrag[4..7] ----
        #pragma unroll
        for (int s4 = 0; s4 < 4; ++s4) {
            f32x4 xa = xv2[2 * s4], xb = xv2[2 * s4 + 1];
            float t0 = xa[0]*xa[0] + xa[1]*xa[1];
            float t1 = xa[2]*xa[2] + xa[3]*xa[3];
            float t2 = xb[0]*xb[0] + xb[1]*xb[1];
            float t3 = xb[2]*xb[2] + xb[3]*xb[3];
            p[s4] += (t0 + t1) + (t2 + t3);
            int s = 4 + s4;
            afrag[s][0] = (short)f2bf(xa[0]); afrag[s][1] = (short)f2bf(xa[1]);
            afrag[s][2] = (short)f2bf(xa[2]); afrag[s][3] = (short)f2bf(xa[3]);
            afrag[s][4] = (short)f2bf(xb[0]); afrag[s][5] = (short)f2bf(xb[1]);
            afrag[s][6] = (short)f2bf(xb[2]); afrag[s][7] = (short)f2bf(xb[3]);
        }

        // ---- prefetch next tile's batch 1: flies through epilogue+sync ----
        if (t + 1 < TPB) {
            const float* xn = xrow(t + 1);
            #pragma unroll
            for (int i = 0; i < 8; ++i)
                xv1[i] = *reinterpret_cast<const f32x4*>(xn + (i >> 1) * 32 + (i & 1) * 4);
        }

        __builtin_amdgcn_s_setprio(1);
        #pragma unroll
        for (int s = 4; s < 8; ++s) {
            #pragma unroll
            for (int f = 0; f < 8; ++f) {
                int ba = ((ch * 128 + f * 16 + c15) * 512) + s * 64 + kch * 16;
                ba ^= ((c15 & 7) << 4);
                s16x8 bfrag = *reinterpret_cast<const s16x8*>(lds_b + ba);
                acc[f] = __builtin_amdgcn_mfma_f32_16x16x32_bf16(afrag[s], bfrag,
                                                                 acc[f], 0, 0, 0);
            }
        }
        __builtin_amdgcn_s_setprio(0);

        // ---- epilogue: student-t + 128-col partial row sums ----
        float xsq = (p[0] + p[1]) + (p[2] + p[3]);
        xsq += __shfl_xor(xsq, 16);
        xsq += __shfl_xor(xsq, 32);
        // lane l now holds xsq of row trow + rg*16 + (l&15)

        float psum[4];
        #pragma unroll
        for (int r = 0; r < 4; ++r) {
            float xrr = __shfl(xsq, kch * 4 + r);
            float s = 0.f;
            #pragma unroll
            for (int f = 0; f < 8; ++f) {
                float d2 = xrr - 2.0f * acc[f][r] + cs[f];
                float qv = __builtin_amdgcn_rcpf(1.0f + d2);  // ALPHA=1 -> exp==1
                acc[f][r] = qv;
                s += qv;
            }
            s += __shfl_xor(s, 1);
            s += __shfl_xor(s, 2);
            s += __shfl_xor(s, 4);
            s += __shfl_xor(s, 8);
            psum[r] = s;   // sum over this wave's 128 cols, row kch*4+r
        }

        // ---- pairwise handshake (no block barrier, no vmcnt drain) ----
        if (c15 == 0) {
            #pragma unroll
            for (int r = 0; r < 4; ++r)
                ls_sum[t][ch][rg][kch * 4 + r] = psum[r];
        }
        asm volatile("s_waitcnt lgkmcnt(0)" ::: "memory");  // sums visible
        if (lane == 0)
            __atomic_store_n(&ls_flag[ch][rg], t + 1, __ATOMIC_RELAXED);

        volatile int* pf = (volatile int*)&ls_flag[ch ^ 1][rg];
        while (*pf <= t) { __builtin_amdgcn_s_sleep(1); }
        asm volatile("" ::: "memory");   // no hoisting of sum reads above spin

        const int row0t = trow + rg * 16;
        #pragma unroll
        for (int r = 0; r < 4; ++r) {
            float other = ls_sum[t][ch ^ 1][rg][kch * 4 + r];
            float inv = __builtin_amdgcn_rcpf(psum[r] + other);
            const size_t orow = (size_t)(row0t + kch * 4 + r) * KCL;
            #pragma unroll
            for (int f = 0; f < 8; ++f) {
                __builtin_nontemporal_store(acc[f][r] * inv,
                                            &out[orow + ch * 128 + f * 16 + c15]);
            }
        }
    }
}

extern "C" void kernel_launch(void* const* d_in, const int* in_sizes, int n_in,
                              void* d_out, int out_size, void* d_ws, size_t ws_size,
                              hipStream_t stream) {
    const float* x        = (const float*)d_in[0];
    const float* clusters = (const float*)d_in[1];
    float* out = (float*)d_out;

    // ws layout: [0, 128KB) clusters as bf16 ; [128KB, +1KB) c_sq f32
    unsigned short* cb  = (unsigned short*)d_ws;
    float*          csq = (float*)((char*)d_ws + (size_t)KCL * DDIM * sizeof(unsigned short));

    prep_kernel<<<KCL, 64, 0, stream>>>(clusters, cb, csq);
    fused_kernel<<<GRID, 512, 0, stream>>>(x, cb, csq, out);
}